// Round 2
// baseline (1143.132 us; speedup 1.0000x reference)
//
#include <hip/hip_runtime.h>
#include <hip/hip_bf16.h>
#include <cstdint>

// ---------------------------------------------------------------------------
// GRU-D: B=256, T=512, D=128, H=256.
// x-path (LOCF, input decay, mask proj, all GEMMs vs inputs) is h-independent
// and precomputed in parallel; the recurrent scan keeps R in registers spread
// across 8 waves (48 frags = 192 VGPRs/wave, pinned vs rematerialization).
// R2 change: column redistribution in k_scan — wave w owns the SAME 32
// h-columns across z, r and hh gates, so z/h/h_d become wave-local REGISTERS
// (q-duplicated; all quads hold identical acc values since A is broadcast).
// Removes three ~120-cyc LDS latency exposures (hd_f32, h_lds, z_buf) from
// the inter-phase critical path and moves the sigmoid off it entirely.
// ---------------------------------------------------------------------------

#define Bsz 256
#define Tsz 512
#define Dsz 128
#define Hsz 256
#define BT  (Bsz * Tsz)          // 131072
#define N3H 768                  // 3*H

typedef __attribute__((ext_vector_type(8))) short   short8;
typedef __attribute__((ext_vector_type(8))) __bf16  bf16x8;
typedef __attribute__((ext_vector_type(4))) float   f32x4;

__device__ __forceinline__ unsigned short f2bf(float f) {
    union { float f; unsigned u; } v; v.f = f;
    unsigned r = v.u + 0x7fffu + ((v.u >> 16) & 1u);   // RNE
    return (unsigned short)(r >> 16);
}
__device__ __forceinline__ float b2f(unsigned short u) {
    union { unsigned u; float f; } v; v.u = ((unsigned)u) << 16;
    return v.f;
}
__device__ __forceinline__ bf16x8 ld_frag(const unsigned short* p) {
    short8 v = *(const short8*)p;
    return __builtin_bit_cast(bf16x8, v);
}

// LDS-only barrier: drains lgkmcnt (ds_write visibility) but NOT vmcnt, so
// global stores (h output) and the t+2 prefetch loads remain in flight.
// All cross-wave traffic at these sync points is through LDS.
__device__ __forceinline__ void barrier_lds() {
    asm volatile("s_waitcnt lgkmcnt(0)\n\ts_barrier" ::: "memory");
}

// ---------------------------------------------------------------------------
// K0: transpose+convert weights to bf16, N-major.
// ---------------------------------------------------------------------------
__global__ void k_pack(const float* __restrict__ kern, const float* __restrict__ maskk,
                       const float* __restrict__ rk,   const float* __restrict__ hdk,
                       unsigned short* __restrict__ KM_T, unsigned short* __restrict__ R_T,
                       unsigned short* __restrict__ W_T) {
    int i = blockIdx.x * 256 + threadIdx.x;
    if (i < N3H * 256) {
        int n = i >> 8, k = i & 255;
        float v = (k < 128) ? kern[k * N3H + n] : maskk[(k - 128) * N3H + n];
        KM_T[i] = f2bf(v);
        R_T[i]  = f2bf(rk[k * N3H + n]);
    } else {
        int j = i - N3H * 256;
        if (j < 256 * 128) {
            int n = j >> 7, k = j & 127;
            W_T[j] = f2bf(hdk[k * 256 + n]);
        }
    }
}

// ---------------------------------------------------------------------------
// K1: LOCF scan, one thread per (b,d).
// ---------------------------------------------------------------------------
__global__ __launch_bounds__(256) void k_locf(
        const float* __restrict__ x, const int* __restrict__ m,
        const float* __restrict__ s, const float* __restrict__ wdi,
        const float* __restrict__ bdi,
        unsigned short* __restrict__ X2, unsigned short* __restrict__ Dt) {
    int gid = blockIdx.x * blockDim.x + threadIdx.x;   // 32768
    int b = gid >> 7, d = gid & 127;
    float w  = wdi[d], bi = bdi[d];
    float x_keep = 0.f, s_prev = 0.f;
    const float* xb  = x + (size_t)b * Tsz * Dsz + d;
    const int*   mb_ = m + (size_t)b * Tsz * Dsz + d;
    const float* sb  = s + (size_t)b * Tsz;
    unsigned short* X2b = X2 + (size_t)b * Tsz * 256 + d;
    unsigned short* Dtb = Dt + (size_t)b * Tsz * 128 + d;
    for (int t0 = 0; t0 < Tsz; t0 += 4) {
        float xv[4], sv[4]; int mv[4];
#pragma unroll
        for (int u = 0; u < 4; u++) {
            xv[u] = xb[(size_t)(t0 + u) * Dsz];
            mv[u] = mb_[(size_t)(t0 + u) * Dsz];
            sv[u] = sb[t0 + u];
        }
#pragma unroll
        for (int u = 0; u < 4; u++) {
            int t = t0 + u;
            float dt  = sv[u] - s_prev;
            float gdi = __expf(-fmaxf(dt * w + bi, 0.f));
            bool  mbt = mv[u] > 0;
            if (mbt) x_keep = xv[u];
            float xe = mbt ? xv[u] : gdi * x_keep;
            if (mbt) s_prev = sv[u];
            X2b[(size_t)t * 256]       = f2bf(xe);
            X2b[(size_t)t * 256 + 128] = f2bf((float)mv[u]);
            Dtb[(size_t)t * 128]       = f2bf(dt);
        }
    }
}

// ---------------------------------------------------------------------------
// K2: bf16 MFMA GEMM, 128x128 tile, BK=32, 4 waves (2x2 of 64x64).
// MODE 0: C = A@B + bias ; MODE 1: C = exp(-relu(A@B + bias)). C bf16.
// ---------------------------------------------------------------------------
template <int MODE, int K, int N>
__global__ __launch_bounds__(256) void k_gemm(
        const unsigned short* __restrict__ A, const unsigned short* __restrict__ Bt,
        const float* __restrict__ bias, unsigned short* __restrict__ C) {
    __shared__ unsigned short As[128][40];
    __shared__ unsigned short Bs[128][40];
    int m0 = blockIdx.x * 128, n0 = blockIdx.y * 128;
    int tid = threadIdx.x, lane = tid & 63, w = tid >> 6;
    int wm = w & 1, wn = w >> 1;
    int r15 = lane & 15, q = lane >> 4;
    int arow = tid >> 2, akg = tid & 3;
    f32x4 acc[4][4];
#pragma unroll
    for (int i = 0; i < 4; i++)
#pragma unroll
        for (int j = 0; j < 4; j++) acc[i][j] = f32x4{0.f, 0.f, 0.f, 0.f};

    for (int kk = 0; kk < K; kk += 32) {
        short8 av0 = *(const short8*)(A  + (size_t)(m0 + arow)      * K + kk + akg * 8);
        short8 av1 = *(const short8*)(A  + (size_t)(m0 + arow + 64) * K + kk + akg * 8);
        short8 bv0 = *(const short8*)(Bt + (size_t)(n0 + arow)      * K + kk + akg * 8);
        short8 bv1 = *(const short8*)(Bt + (size_t)(n0 + arow + 64) * K + kk + akg * 8);
        *(short8*)&As[arow][akg * 8]      = av0;
        *(short8*)&As[arow + 64][akg * 8] = av1;
        *(short8*)&Bs[arow][akg * 8]      = bv0;
        *(short8*)&Bs[arow + 64][akg * 8] = bv1;
        __syncthreads();
        bf16x8 af[4], bf[4];
#pragma unroll
        for (int i = 0; i < 4; i++) af[i] = ld_frag(&As[wm * 64 + i * 16 + r15][q * 8]);
#pragma unroll
        for (int j = 0; j < 4; j++) bf[j] = ld_frag(&Bs[wn * 64 + j * 16 + r15][q * 8]);
#pragma unroll
        for (int i = 0; i < 4; i++)
#pragma unroll
            for (int j = 0; j < 4; j++)
                acc[i][j] = __builtin_amdgcn_mfma_f32_16x16x32_bf16(af[i], bf[j], acc[i][j], 0, 0, 0);
        __syncthreads();
    }
#pragma unroll
    for (int i = 0; i < 4; i++)
#pragma unroll
        for (int j = 0; j < 4; j++) {
            int col = n0 + wn * 64 + j * 16 + r15;
            float bs = bias[col];
#pragma unroll
            for (int rg = 0; rg < 4; rg++) {
                int row = m0 + wm * 64 + i * 16 + q * 4 + rg;
                float v = acc[i][j][rg] + bs;
                if (MODE == 1) v = __expf(-fmaxf(v, 0.f));
                C[(size_t)row * N + col] = f2bf(v);
            }
        }
}

// ---------------------------------------------------------------------------
// K3: recurrent scan. 256 blocks (one per batch), 8 waves (512 thr).
// Column redistribution: wave w owns h-columns [w*32, w*32+32) through ALL
// gates: z tiles at cols w*32{+0,+16}, r tiles at 256+w*32{+0,+16}, hh tiles
// at 512+w*32{+0,+16}. A-operand is the h_d / u vector broadcast to all 16
// rows, so every lane's acc[nt][0] holds the result for col nt_base+r15,
// identical across the 4 lane-quads q. Consequences:
//   - pre_z, h, h_d live in per-lane REGISTERS (q-duplicated), never in LDS.
//   - phase-2 epilogue = u = pre_r * hd_reg (register) + ds_write: no LDS
//     read latency between the zr MFMAs and the barrier gating phase 3.
//   - sigmoid(z) is computed after phase-3 MFMA issue, overlapping the pipe.
// LDS per step: u_bf + hd_bf broadcast operands only. 2 lgkmcnt-only
// barriers/step. 48 frags (192 regs) pinned via asm vs rematerialization.
// ---------------------------------------------------------------------------
__global__ __launch_bounds__(512, 2) void k_scan(
        const unsigned short* __restrict__ Apre, const unsigned short* __restrict__ G,
        const unsigned short* __restrict__ R_T, float* __restrict__ out) {
    int b = blockIdx.x;
    int tid = threadIdx.x, lane = tid & 63, w = tid >> 6;
    int r15 = lane & 15, q = lane >> 4;

    __shared__ __align__(16) unsigned short hd_bf[256];
    __shared__ __align__(16) unsigned short u_bf[256];
    __shared__ __align__(16) unsigned short ap_l[2][768];
    __shared__ __align__(16) unsigned short g_l[2][256];

    // ---- persistent weight fragments (192 regs/wave) ----
    // fzr[0..1]: z cols  w*32 + nt*16 + r15
    // fzr[2..3]: r cols  256 + w*32 + (nt-2)*16 + r15
    // fh [0..1]: hh cols 512 + w*32 + nt*16 + r15
    bf16x8 fzr[4][8];
    bf16x8 fh[2][8];
#pragma unroll
    for (int nt = 0; nt < 4; nt++) {
        int col = (nt < 2) ? (w * 32 + nt * 16 + r15)
                           : (256 + w * 32 + (nt - 2) * 16 + r15);
        const unsigned short* base = R_T + (size_t)col * 256 + q * 8;
#pragma unroll
        for (int kt = 0; kt < 8; kt++) {
            fzr[nt][kt] = ld_frag(base + kt * 32);
            asm volatile("" : "+v"(fzr[nt][kt]));   // pin: no remat in loop
        }
    }
#pragma unroll
    for (int nt = 0; nt < 2; nt++) {
        const unsigned short* base = R_T + (size_t)(512 + w * 32 + nt * 16 + r15) * 256 + q * 8;
#pragma unroll
        for (int kt = 0; kt < 8; kt++) {
            fh[nt][kt] = ld_frag(base + kt * 32);
            asm volatile("" : "+v"(fh[nt][kt]));
        }
    }

    if (tid < 256) hd_bf[tid] = 0;

    const unsigned short* aprow = Apre + (size_t)b * Tsz * N3H;
    const unsigned short* grow  = G    + (size_t)b * Tsz * 256;

    // preload t=0 and t=1 rows (ap: 768 each, g: 256 each), uint2 = 4 ushorts
    if (tid < 192)      *(uint2*)&ap_l[0][tid * 4]         = *(const uint2*)(aprow + tid * 4);
    else if (tid < 384) *(uint2*)&ap_l[1][(tid-192) * 4]   = *(const uint2*)(aprow + N3H + (tid-192) * 4);
    else if (tid < 448) *(uint2*)&g_l[0][(tid-384) * 4]    = *(const uint2*)(grow + (tid-384) * 4);
    else                *(uint2*)&g_l[1][(tid-448) * 4]    = *(const uint2*)(grow + 256 + (tid-448) * 4);
    __syncthreads();

    // per-lane recurrent state for this wave's 2 columns (c0, c0+16),
    // duplicated across the 4 quads q (identical values, deterministic ops).
    int c0 = w * 32 + r15;
    float h0 = 0.f, h1 = 0.f;        // h_{t-1}
    float hd0 = 0.f, hd1 = 0.f;      // gamma_dh(t) * h_{t-1} (f32)

    float* outb = out + (size_t)b * Tsz * 256;
    for (int t = 0; t < Tsz; t++) {
        int buf = t & 1;
        int tp2 = (t + 2 < Tsz) ? t + 2 : Tsz - 1;
        // prefetch row t+2 into a register (1 VGPR/thread)
        unsigned pf;
        if (tid < 384) pf = *(const unsigned*)(aprow + (size_t)tp2 * N3H + tid * 2);
        else           pf = *(const unsigned*)(grow  + (size_t)tp2 * 256 + (tid - 384) * 2);

        // ---- phase A: zr = Apre[:512] + h_d @ R_zr (wave-local columns) ----
        f32x4 acc[4];
#pragma unroll
        for (int nt = 0; nt < 4; nt++) acc[nt] = f32x4{0.f, 0.f, 0.f, 0.f};
#pragma unroll
        for (int kt = 0; kt < 8; kt++) {
            bf16x8 afr = ld_frag(&hd_bf[kt * 32 + q * 8]);   // quad-uniform broadcast
#pragma unroll
            for (int nt = 0; nt < 4; nt++)
                acc[nt] = __builtin_amdgcn_mfma_f32_16x16x32_bf16(afr, fzr[nt][kt], acc[nt], 0, 0, 0);
        }
        // epilogue A: compute u = pre_r * h_d (registers only) and publish it.
        // pre_z stays in registers; its sigmoid is deferred past the barrier.
        float pz0 = acc[0][0] + b2f(ap_l[buf][c0]);
        float pz1 = acc[1][0] + b2f(ap_l[buf][c0 + 16]);
        float pr0 = acc[2][0] + b2f(ap_l[buf][256 + c0]);
        float pr1 = acc[3][0] + b2f(ap_l[buf][256 + c0 + 16]);
        float u0 = pr0 * hd0;
        float u1 = pr1 * hd1;
        if (q < 2) u_bf[c0 + q * 16] = f2bf(q == 0 ? u0 : u1);
        barrier_lds();

        // ---- phase B: hh = tanh(Apre[512:] + u @ Rh); h update ----
        f32x4 acch[2];
#pragma unroll
        for (int nt = 0; nt < 2; nt++) acch[nt] = f32x4{0.f, 0.f, 0.f, 0.f};
#pragma unroll
        for (int kt = 0; kt < 8; kt++) {
            bf16x8 afr = ld_frag(&u_bf[kt * 32 + q * 8]);
#pragma unroll
            for (int nt = 0; nt < 2; nt++)
                acch[nt] = __builtin_amdgcn_mfma_f32_16x16x32_bf16(afr, fh[nt][kt], acch[nt], 0, 0, 0);
        }
        // sigmoid of z overlaps the MFMA window (register-local, no ordering)
        float z0 = 1.f / (1.f + __expf(-pz0));
        float z1 = 1.f / (1.f + __expf(-pz1));
        // epilogue B: tanh + h update, all in registers
        float ph0 = acch[0][0] + b2f(ap_l[buf][512 + c0]);
        float ph1 = acch[1][0] + b2f(ap_l[buf][512 + c0 + 16]);
        float e0 = __expf(2.f * ph0), e1 = __expf(2.f * ph1);
        float hh0 = 1.f - 2.f / (e0 + 1.f);
        float hh1 = 1.f - 2.f / (e1 + 1.f);
        float hn0 = z0 * h0 + (1.f - z0) * hh0;
        float hn1 = z1 * h1 + (1.f - z1) * hh1;
        h0 = hn0; h1 = hn1;
        if (q < 2) outb[(size_t)t * 256 + c0 + q * 16] = (q == 0 ? hn0 : hn1);
        float g0 = b2f(g_l[buf ^ 1][c0]);
        float g1 = b2f(g_l[buf ^ 1][c0 + 16]);
        hd0 = g0 * hn0;                      // gamma_dh(t+1) * h_t
        hd1 = g1 * hn1;
        if (q < 2) hd_bf[c0 + q * 16] = f2bf(q == 0 ? hd0 : hd1);
        barrier_lds();

        // stash prefetched t+2 row into buf (t's data is dead now); the next
        // iteration's first barrier orders these writes before any consumer.
        if (tid < 384) *(unsigned*)&ap_l[buf][tid * 2] = pf;
        else           *(unsigned*)&g_l[buf][(tid - 384) * 2] = pf;
    }
}

// ---------------------------------------------------------------------------
extern "C" void kernel_launch(void* const* d_in, const int* in_sizes, int n_in,
                              void* d_out, int out_size, void* d_ws, size_t ws_size,
                              hipStream_t stream) {
    const float* x    = (const float*)d_in[0];
    const int*   m    = (const int*)  d_in[1];
    const float* s    = (const float*)d_in[2];
    const float* kern = (const float*)d_in[3];
    const float* rk   = (const float*)d_in[4];
    const float* mk   = (const float*)d_in[5];
    const float* bias = (const float*)d_in[6];
    const float* wdi  = (const float*)d_in[7];
    const float* bdi  = (const float*)d_in[8];
    const float* hdk  = (const float*)d_in[9];
    const float* hdb  = (const float*)d_in[10];
    float* out = (float*)d_out;

    char* ws = (char*)d_ws;
    size_t off = 0;
    auto alloc = [&](size_t bytes) -> void* {
        void* p = ws + off; off += (bytes + 255) & ~(size_t)255; return p;
    };
    unsigned short* X2   = (unsigned short*)alloc((size_t)BT * 256 * 2); // 67 MB
    unsigned short* Dt   = (unsigned short*)alloc((size_t)BT * 128 * 2); // 33.6 MB
    unsigned short* Apre = (unsigned short*)alloc((size_t)BT * N3H * 2); // 201 MB
    unsigned short* Gm   = (unsigned short*)alloc((size_t)BT * 256 * 2); // 67 MB
    unsigned short* KM_T = (unsigned short*)alloc((size_t)N3H * 256 * 2);
    unsigned short* R_T  = (unsigned short*)alloc((size_t)N3H * 256 * 2);
    unsigned short* W_T  = (unsigned short*)alloc((size_t)256 * 128 * 2);
    (void)ws_size; (void)in_sizes; (void)n_in; (void)out_size;

    k_pack<<<dim3((N3H * 256 + 256 * 128 + 255) / 256), dim3(256), 0, stream>>>(
        kern, mk, rk, hdk, KM_T, R_T, W_T);
    k_locf<<<dim3(Bsz * Dsz / 256), dim3(256), 0, stream>>>(x, m, s, wdi, bdi, X2, Dt);
    k_gemm<0, 256, N3H><<<dim3(BT / 128, N3H / 128), dim3(256), 0, stream>>>(X2, KM_T, bias, Apre);
    k_gemm<1, 128, 256><<<dim3(BT / 128, 256 / 128), dim3(256), 0, stream>>>(Dt, W_T, hdb, Gm);
    k_scan<<<dim3(Bsz), dim3(512), 0, stream>>>(Apre, Gm, R_T, out);
}

// Round 3
// 1066.347 us; speedup vs baseline: 1.0720x; 1.0720x over previous
//
#include <hip/hip_runtime.h>
#include <hip/hip_bf16.h>
#include <cstdint>

// ---------------------------------------------------------------------------
// GRU-D: B=256, T=512, D=128, H=256.
// x-path (LOCF, input decay, mask proj, all GEMMs vs inputs) is h-independent
// and precomputed in parallel; the recurrent scan keeps R in registers spread
// across 8 waves (48 frags = 192 VGPRs/wave, pinned vs rematerialization).
// R3: R2's wave-local column layout (state in registers) + R1's lane economy.
// Each lane SELECTS one column (q<2 -> c0, q>=2 -> c0+16) via cndmask on the
// quad-identical accumulators, then runs the per-column epilogue chain once:
// 1 sigmoid + 1 tanh + 1 h-update per lane (R2 redundantly did 2 of each —
// VALU cost is per-instruction, not per-useful-lane; that was the R2
// regression). ap_l/g_l scalar reads hoisted under the MFMA windows.
// ---------------------------------------------------------------------------

#define Bsz 256
#define Tsz 512
#define Dsz 128
#define Hsz 256
#define BT  (Bsz * Tsz)          // 131072
#define N3H 768                  // 3*H

typedef __attribute__((ext_vector_type(8))) short   short8;
typedef __attribute__((ext_vector_type(8))) __bf16  bf16x8;
typedef __attribute__((ext_vector_type(4))) float   f32x4;

__device__ __forceinline__ unsigned short f2bf(float f) {
    union { float f; unsigned u; } v; v.f = f;
    unsigned r = v.u + 0x7fffu + ((v.u >> 16) & 1u);   // RNE
    return (unsigned short)(r >> 16);
}
__device__ __forceinline__ float b2f(unsigned short u) {
    union { unsigned u; float f; } v; v.u = ((unsigned)u) << 16;
    return v.f;
}
__device__ __forceinline__ bf16x8 ld_frag(const unsigned short* p) {
    short8 v = *(const short8*)p;
    return __builtin_bit_cast(bf16x8, v);
}

// LDS-only barrier: drains lgkmcnt (ds_write visibility) but NOT vmcnt, so
// global stores (h output) and the t+2 prefetch loads remain in flight.
// All cross-wave traffic at these sync points is through LDS.
__device__ __forceinline__ void barrier_lds() {
    asm volatile("s_waitcnt lgkmcnt(0)\n\ts_barrier" ::: "memory");
}

// ---------------------------------------------------------------------------
// K0: transpose+convert weights to bf16, N-major.
// ---------------------------------------------------------------------------
__global__ void k_pack(const float* __restrict__ kern, const float* __restrict__ maskk,
                       const float* __restrict__ rk,   const float* __restrict__ hdk,
                       unsigned short* __restrict__ KM_T, unsigned short* __restrict__ R_T,
                       unsigned short* __restrict__ W_T) {
    int i = blockIdx.x * 256 + threadIdx.x;
    if (i < N3H * 256) {
        int n = i >> 8, k = i & 255;
        float v = (k < 128) ? kern[k * N3H + n] : maskk[(k - 128) * N3H + n];
        KM_T[i] = f2bf(v);
        R_T[i]  = f2bf(rk[k * N3H + n]);
    } else {
        int j = i - N3H * 256;
        if (j < 256 * 128) {
            int n = j >> 7, k = j & 127;
            W_T[j] = f2bf(hdk[k * 256 + n]);
        }
    }
}

// ---------------------------------------------------------------------------
// K1: LOCF scan, one thread per (b,d).
// ---------------------------------------------------------------------------
__global__ __launch_bounds__(256) void k_locf(
        const float* __restrict__ x, const int* __restrict__ m,
        const float* __restrict__ s, const float* __restrict__ wdi,
        const float* __restrict__ bdi,
        unsigned short* __restrict__ X2, unsigned short* __restrict__ Dt) {
    int gid = blockIdx.x * blockDim.x + threadIdx.x;   // 32768
    int b = gid >> 7, d = gid & 127;
    float w  = wdi[d], bi = bdi[d];
    float x_keep = 0.f, s_prev = 0.f;
    const float* xb  = x + (size_t)b * Tsz * Dsz + d;
    const int*   mb_ = m + (size_t)b * Tsz * Dsz + d;
    const float* sb  = s + (size_t)b * Tsz;
    unsigned short* X2b = X2 + (size_t)b * Tsz * 256 + d;
    unsigned short* Dtb = Dt + (size_t)b * Tsz * 128 + d;
    for (int t0 = 0; t0 < Tsz; t0 += 4) {
        float xv[4], sv[4]; int mv[4];
#pragma unroll
        for (int u = 0; u < 4; u++) {
            xv[u] = xb[(size_t)(t0 + u) * Dsz];
            mv[u] = mb_[(size_t)(t0 + u) * Dsz];
            sv[u] = sb[t0 + u];
        }
#pragma unroll
        for (int u = 0; u < 4; u++) {
            int t = t0 + u;
            float dt  = sv[u] - s_prev;
            float gdi = __expf(-fmaxf(dt * w + bi, 0.f));
            bool  mbt = mv[u] > 0;
            if (mbt) x_keep = xv[u];
            float xe = mbt ? xv[u] : gdi * x_keep;
            if (mbt) s_prev = sv[u];
            X2b[(size_t)t * 256]       = f2bf(xe);
            X2b[(size_t)t * 256 + 128] = f2bf((float)mv[u]);
            Dtb[(size_t)t * 128]       = f2bf(dt);
        }
    }
}

// ---------------------------------------------------------------------------
// K2: bf16 MFMA GEMM, 128x128 tile, BK=32, 4 waves (2x2 of 64x64).
// MODE 0: C = A@B + bias ; MODE 1: C = exp(-relu(A@B + bias)). C bf16.
// ---------------------------------------------------------------------------
template <int MODE, int K, int N>
__global__ __launch_bounds__(256) void k_gemm(
        const unsigned short* __restrict__ A, const unsigned short* __restrict__ Bt,
        const float* __restrict__ bias, unsigned short* __restrict__ C) {
    __shared__ unsigned short As[128][40];
    __shared__ unsigned short Bs[128][40];
    int m0 = blockIdx.x * 128, n0 = blockIdx.y * 128;
    int tid = threadIdx.x, lane = tid & 63, w = tid >> 6;
    int wm = w & 1, wn = w >> 1;
    int r15 = lane & 15, q = lane >> 4;
    int arow = tid >> 2, akg = tid & 3;
    f32x4 acc[4][4];
#pragma unroll
    for (int i = 0; i < 4; i++)
#pragma unroll
        for (int j = 0; j < 4; j++) acc[i][j] = f32x4{0.f, 0.f, 0.f, 0.f};

    for (int kk = 0; kk < K; kk += 32) {
        short8 av0 = *(const short8*)(A  + (size_t)(m0 + arow)      * K + kk + akg * 8);
        short8 av1 = *(const short8*)(A  + (size_t)(m0 + arow + 64) * K + kk + akg * 8);
        short8 bv0 = *(const short8*)(Bt + (size_t)(n0 + arow)      * K + kk + akg * 8);
        short8 bv1 = *(const short8*)(Bt + (size_t)(n0 + arow + 64) * K + kk + akg * 8);
        *(short8*)&As[arow][akg * 8]      = av0;
        *(short8*)&As[arow + 64][akg * 8] = av1;
        *(short8*)&Bs[arow][akg * 8]      = bv0;
        *(short8*)&Bs[arow + 64][akg * 8] = bv1;
        __syncthreads();
        bf16x8 af[4], bf[4];
#pragma unroll
        for (int i = 0; i < 4; i++) af[i] = ld_frag(&As[wm * 64 + i * 16 + r15][q * 8]);
#pragma unroll
        for (int j = 0; j < 4; j++) bf[j] = ld_frag(&Bs[wn * 64 + j * 16 + r15][q * 8]);
#pragma unroll
        for (int i = 0; i < 4; i++)
#pragma unroll
            for (int j = 0; j < 4; j++)
                acc[i][j] = __builtin_amdgcn_mfma_f32_16x16x32_bf16(af[i], bf[j], acc[i][j], 0, 0, 0);
        __syncthreads();
    }
#pragma unroll
    for (int i = 0; i < 4; i++)
#pragma unroll
        for (int j = 0; j < 4; j++) {
            int col = n0 + wn * 64 + j * 16 + r15;
            float bs = bias[col];
#pragma unroll
            for (int rg = 0; rg < 4; rg++) {
                int row = m0 + wm * 64 + i * 16 + q * 4 + rg;
                float v = acc[i][j][rg] + bs;
                if (MODE == 1) v = __expf(-fmaxf(v, 0.f));
                C[(size_t)row * N + col] = f2bf(v);
            }
        }
}

// ---------------------------------------------------------------------------
// K3: recurrent scan. 256 blocks (one per batch), 8 waves (512 thr).
// Wave w owns h-columns [w*32, w*32+32) through ALL gates (z, r, hh).
// A-operand is the h_d / u vector broadcast to all 16 MFMA rows, so every
// lane's acc[nt][0] holds the result for col nt_base + r15, identical across
// the 4 lane-quads. Lane SELECTION: quads 0-1 own col c0 = w*32+r15, quads
// 2-3 own c0+16 (3 cndmasks pick the right acc element). Per-lane epilogue
// chain is then a SINGLE column's worth of work:
//   epiA: pz/pr select + u = pr*hd_reg (register) + cond ds_write (q0,q2)
//   epiB: ph select + tanh + h update + hd_reg = g*hn + cond writes
// ap_l reads hoisted to step start, g_l read to phase-B start (latency under
// MFMA windows). LDS per step: u_bf + hd_bf broadcast operands only.
// 2 lgkmcnt-only barriers/step. 48 frags (192 regs) pinned via asm.
// ---------------------------------------------------------------------------
__global__ __launch_bounds__(512, 2) void k_scan(
        const unsigned short* __restrict__ Apre, const unsigned short* __restrict__ G,
        const unsigned short* __restrict__ R_T, float* __restrict__ out) {
    int b = blockIdx.x;
    int tid = threadIdx.x, lane = tid & 63, w = tid >> 6;
    int r15 = lane & 15, q = lane >> 4;

    __shared__ __align__(16) unsigned short hd_bf[256];
    __shared__ __align__(16) unsigned short u_bf[256];
    __shared__ __align__(16) unsigned short ap_l[2][768];
    __shared__ __align__(16) unsigned short g_l[2][256];

    // ---- persistent weight fragments (192 regs/wave) ----
    // fzr[0..1]: z cols  w*32 + nt*16 + r15
    // fzr[2..3]: r cols  256 + w*32 + (nt-2)*16 + r15
    // fh [0..1]: hh cols 512 + w*32 + nt*16 + r15
    bf16x8 fzr[4][8];
    bf16x8 fh[2][8];
#pragma unroll
    for (int nt = 0; nt < 4; nt++) {
        int col = (nt < 2) ? (w * 32 + nt * 16 + r15)
                           : (256 + w * 32 + (nt - 2) * 16 + r15);
        const unsigned short* base = R_T + (size_t)col * 256 + q * 8;
#pragma unroll
        for (int kt = 0; kt < 8; kt++) {
            fzr[nt][kt] = ld_frag(base + kt * 32);
            asm volatile("" : "+v"(fzr[nt][kt]));   // pin: no remat in loop
        }
    }
#pragma unroll
    for (int nt = 0; nt < 2; nt++) {
        const unsigned short* base = R_T + (size_t)(512 + w * 32 + nt * 16 + r15) * 256 + q * 8;
#pragma unroll
        for (int kt = 0; kt < 8; kt++) {
            fh[nt][kt] = ld_frag(base + kt * 32);
            asm volatile("" : "+v"(fh[nt][kt]));
        }
    }

    if (tid < 256) hd_bf[tid] = 0;

    const unsigned short* aprow = Apre + (size_t)b * Tsz * N3H;
    const unsigned short* grow  = G    + (size_t)b * Tsz * 256;

    // preload t=0 and t=1 rows (ap: 768 each, g: 256 each), uint2 = 4 ushorts
    if (tid < 192)      *(uint2*)&ap_l[0][tid * 4]         = *(const uint2*)(aprow + tid * 4);
    else if (tid < 384) *(uint2*)&ap_l[1][(tid-192) * 4]   = *(const uint2*)(aprow + N3H + (tid-192) * 4);
    else if (tid < 448) *(uint2*)&g_l[0][(tid-384) * 4]    = *(const uint2*)(grow + (tid-384) * 4);
    else                *(uint2*)&g_l[1][(tid-448) * 4]    = *(const uint2*)(grow + 256 + (tid-448) * 4);
    __syncthreads();

    // Lane's owned column: quads 0-1 -> c0, quads 2-3 -> c0+16 (2x redundant
    // across the 16-lane pairs within each half; instruction count is what
    // matters, and every chain below is issued once wave-wide).
    bool hiSel  = (q >= 2);
    bool writer = ((q & 1) == 0);            // q==0 or q==2: one writer per col
    int  col    = w * 32 + (hiSel ? 16 : 0) + r15;
    float h_reg  = 0.f;                      // h_{t-1}[col]
    float hd_reg = 0.f;                      // gamma_dh(t) * h_{t-1} [col]

    float* outb = out + (size_t)b * Tsz * 256;
    for (int t = 0; t < Tsz; t++) {
        int buf = t & 1;
        int tp2 = (t + 2 < Tsz) ? t + 2 : Tsz - 1;
        // prefetch row t+2 into a register (1 VGPR/thread)
        unsigned pf;
        if (tid < 384) pf = *(const unsigned*)(aprow + (size_t)tp2 * N3H + tid * 2);
        else           pf = *(const unsigned*)(grow  + (size_t)tp2 * 256 + (tid - 384) * 2);

        // hoisted scalar LDS reads — latency hides under phase-A MFMAs
        unsigned short a_z = ap_l[buf][col];
        unsigned short a_r = ap_l[buf][256 + col];
        unsigned short a_h = ap_l[buf][512 + col];

        // ---- phase A: zr = Apre[:512] + h_d @ R_zr (wave-local columns) ----
        f32x4 acc[4];
#pragma unroll
        for (int nt = 0; nt < 4; nt++) acc[nt] = f32x4{0.f, 0.f, 0.f, 0.f};
#pragma unroll
        for (int kt = 0; kt < 8; kt++) {
            bf16x8 afr = ld_frag(&hd_bf[kt * 32 + q * 8]);   // quad-uniform broadcast
#pragma unroll
            for (int nt = 0; nt < 4; nt++)
                acc[nt] = __builtin_amdgcn_mfma_f32_16x16x32_bf16(afr, fzr[nt][kt], acc[nt], 0, 0, 0);
        }
        // epilogue A: select own column, u = pre_r * hd (registers), publish.
        float pz = (hiSel ? acc[1][0] : acc[0][0]) + b2f(a_z);
        float pr = (hiSel ? acc[3][0] : acc[2][0]) + b2f(a_r);
        float u  = pr * hd_reg;
        if (writer) u_bf[col] = f2bf(u);
        barrier_lds();

        // ---- phase B: hh = tanh(Apre[512:] + u @ Rh); h update ----
        unsigned short g_v = g_l[buf ^ 1][col];   // hoisted under phase-B MFMAs
        f32x4 acch[2];
#pragma unroll
        for (int nt = 0; nt < 2; nt++) acch[nt] = f32x4{0.f, 0.f, 0.f, 0.f};
#pragma unroll
        for (int kt = 0; kt < 8; kt++) {
            bf16x8 afr = ld_frag(&u_bf[kt * 32 + q * 8]);
#pragma unroll
            for (int nt = 0; nt < 2; nt++)
                acch[nt] = __builtin_amdgcn_mfma_f32_16x16x32_bf16(afr, fh[nt][kt], acch[nt], 0, 0, 0);
        }
        // sigmoid of z overlaps the MFMA window (register-local, no ordering)
        float z = 1.f / (1.f + __expf(-pz));
        // epilogue B: one column's chain per lane, all in registers
        float ph = (hiSel ? acch[1][0] : acch[0][0]) + b2f(a_h);
        float e2 = __expf(2.f * ph);
        float hh = 1.f - 2.f / (e2 + 1.f);          // tanh, inf-safe
        float hn = z * h_reg + (1.f - z) * hh;
        h_reg = hn;
        if (writer) outb[(size_t)t * 256 + col] = hn;
        hd_reg = b2f(g_v) * hn;                     // gamma_dh(t+1) * h_t
        if (writer) hd_bf[col] = f2bf(hd_reg);
        barrier_lds();

        // stash prefetched t+2 row into buf (t's data is dead now); the next
        // iteration's first barrier orders these writes before any consumer.
        if (tid < 384) *(unsigned*)&ap_l[buf][tid * 2] = pf;
        else           *(unsigned*)&g_l[buf][(tid - 384) * 2] = pf;
    }
}

// ---------------------------------------------------------------------------
extern "C" void kernel_launch(void* const* d_in, const int* in_sizes, int n_in,
                              void* d_out, int out_size, void* d_ws, size_t ws_size,
                              hipStream_t stream) {
    const float* x    = (const float*)d_in[0];
    const int*   m    = (const int*)  d_in[1];
    const float* s    = (const float*)d_in[2];
    const float* kern = (const float*)d_in[3];
    const float* rk   = (const float*)d_in[4];
    const float* mk   = (const float*)d_in[5];
    const float* bias = (const float*)d_in[6];
    const float* wdi  = (const float*)d_in[7];
    const float* bdi  = (const float*)d_in[8];
    const float* hdk  = (const float*)d_in[9];
    const float* hdb  = (const float*)d_in[10];
    float* out = (float*)d_out;

    char* ws = (char*)d_ws;
    size_t off = 0;
    auto alloc = [&](size_t bytes) -> void* {
        void* p = ws + off; off += (bytes + 255) & ~(size_t)255; return p;
    };
    unsigned short* X2   = (unsigned short*)alloc((size_t)BT * 256 * 2); // 67 MB
    unsigned short* Dt   = (unsigned short*)alloc((size_t)BT * 128 * 2); // 33.6 MB
    unsigned short* Apre = (unsigned short*)alloc((size_t)BT * N3H * 2); // 201 MB
    unsigned short* Gm   = (unsigned short*)alloc((size_t)BT * 256 * 2); // 67 MB
    unsigned short* KM_T = (unsigned short*)alloc((size_t)N3H * 256 * 2);
    unsigned short* R_T  = (unsigned short*)alloc((size_t)N3H * 256 * 2);
    unsigned short* W_T  = (unsigned short*)alloc((size_t)256 * 128 * 2);
    (void)ws_size; (void)in_sizes; (void)n_in; (void)out_size;

    k_pack<<<dim3((N3H * 256 + 256 * 128 + 255) / 256), dim3(256), 0, stream>>>(
        kern, mk, rk, hdk, KM_T, R_T, W_T);
    k_locf<<<dim3(Bsz * Dsz / 256), dim3(256), 0, stream>>>(x, m, s, wdi, bdi, X2, Dt);
    k_gemm<0, 256, N3H><<<dim3(BT / 128, N3H / 128), dim3(256), 0, stream>>>(X2, KM_T, bias, Apre);
    k_gemm<1, 128, 256><<<dim3(BT / 128, 256 / 128), dim3(256), 0, stream>>>(Dt, W_T, hdb, Gm);
    k_scan<<<dim3(Bsz), dim3(512), 0, stream>>>(Apre, Gm, R_T, out);
}